// Round 1
// baseline (15569.826 us; speedup 1.0000x reference)
//
#include <hip/hip_runtime.h>

#define Bn 32
#define Tn 512
#define Cn 8
#define Hn 256
#define Gn 1024           // 4*Hn
#define KP 260            // padded LDS row pitch (floats); 260*4=1040B, 16B aligned, bank-safe
#define NTHR 256
#define NBLK 256          // 8 channels * 32 slices
#define CBH (Cn*Bn*Hn)    // 65536 floats

__device__ __forceinline__ float sum4(const float4 v) { return (v.x + v.y) + (v.z + v.w); }
__device__ __forceinline__ float sigmf(float v) { return 1.0f / (1.0f + __expf(-v)); }
__device__ __forceinline__ float tanh_f(float v) { return 1.0f - 2.0f / (__expf(2.0f * v) + 1.0f); }

// stage one 32-row x 256-col weight slice into LDS (rows = 4 gates x 8 h-idx of this slice)
__device__ __forceinline__ void stage_w(float* wb, const float* __restrict__ Wc, int s, int tid) {
#pragma unroll
    for (int it = 0; it < 8; ++it) {
        const int idx = it * NTHR + tid;
        const int row = idx >> 6, k4 = idx & 63;
        const int gr = (row >> 3) * Hn + s * 8 + (row & 7);   // global gate row
        *(float4*)(wb + row * KP + k4 * 4) = *(const float4*)(Wc + gr * Hn + k4 * 4);
    }
}
// stage h-state [32 b][256 h] into LDS
__device__ __forceinline__ void stage_h(float* hb, const float* __restrict__ src, int tid) {
#pragma unroll
    for (int it = 0; it < 8; ++it) {
        const int idx = it * NTHR + tid;
        const int row = idx >> 6, k4 = idx & 63;
        *(float4*)(hb + row * KP + k4 * 4) = *(const float4*)(src + row * Hn + k4 * 4);
    }
}

// 2x2 register-tile GEMM fragment: rows r0,r1 x batches b0,b1, k=256 from LDS
__device__ __forceinline__ void gemm2x2(const float* wb, const float* hb,
                                        int r0, int r1, int b0, int b1,
                                        float4& a00, float4& a01, float4& a10, float4& a11) {
    const float4* wr0 = (const float4*)(wb + r0 * KP);
    const float4* wr1 = (const float4*)(wb + r1 * KP);
    const float4* hr0 = (const float4*)(hb + b0 * KP);
    const float4* hr1 = (const float4*)(hb + b1 * KP);
#pragma unroll 4
    for (int k = 0; k < Hn / 4; ++k) {
        const float4 w0 = wr0[k], w1 = wr1[k], h0 = hr0[k], h1 = hr1[k];
        a00.x = fmaf(w0.x, h0.x, a00.x); a00.y = fmaf(w0.y, h0.y, a00.y);
        a00.z = fmaf(w0.z, h0.z, a00.z); a00.w = fmaf(w0.w, h0.w, a00.w);
        a01.x = fmaf(w0.x, h1.x, a01.x); a01.y = fmaf(w0.y, h1.y, a01.y);
        a01.z = fmaf(w0.z, h1.z, a01.z); a01.w = fmaf(w0.w, h1.w, a01.w);
        a10.x = fmaf(w1.x, h0.x, a10.x); a10.y = fmaf(w1.y, h0.y, a10.y);
        a10.z = fmaf(w1.z, h0.z, a10.z); a10.w = fmaf(w1.w, h0.w, a10.w);
        a11.x = fmaf(w1.x, h1.x, a11.x); a11.y = fmaf(w1.y, h1.y, a11.y);
        a11.z = fmaf(w1.z, h1.z, a11.z); a11.w = fmaf(w1.w, h1.w, a11.w);
    }
}

// per-channel barrier: 32 wgs, monotone counter, device-scope
__device__ __forceinline__ void chan_barrier(unsigned* cnt, unsigned target) {
    __syncthreads();
    if (threadIdx.x == 0) {
        __threadfence();
        atomicAdd(cnt, 1u);
        while (__hip_atomic_load(cnt, __ATOMIC_RELAXED, __HIP_MEMORY_SCOPE_AGENT) < target)
            __builtin_amdgcn_s_sleep(2);
        __threadfence();
    }
    __syncthreads();
}

__global__ void __launch_bounds__(NTHR, 1)
lstm_fused(const float* __restrict__ x,
           const float* __restrict__ Wih1, const float* __restrict__ Whh1,
           const float* __restrict__ bih1, const float* __restrict__ bhh1,
           const float* __restrict__ Wih2, const float* __restrict__ Whh2,
           const float* __restrict__ bih2, const float* __restrict__ bhh2,
           const float* __restrict__ Wlin, const float* __restrict__ blin,
           float* __restrict__ out, float* __restrict__ ws) {
    extern __shared__ float smem[];
    float* hbuf = smem;                 // [32][KP]
    float* wbuf = smem + 32 * KP;       // [32][KP]
    float* gbuf = smem + 64 * KP;       // [32][32] gate exchange / out partials
    float* hout = gbuf + 32 * 32;       // [256] h staging for coalesced global write

    const int tid = threadIdx.x;
    const int wg = blockIdx.x;
    const int c = wg >> 5;              // channel
    const int s = wg & 31;              // slice (8 h-indices)

    float* H1 = ws;                     // [2][C][B][H] double-buffered h1
    float* H2 = ws + 2 * CBH;           // [2][C][B][H] double-buffered h2
    unsigned* bars = (unsigned*)(ws + 4 * CBH);  // 8 counters, 64B apart

    // GEMM tile mapping: rows {rp, rp+16} x batches {bp, bp+16} (bank-friendly)
    const int rp = tid >> 4;
    const int bp = tid & 15;
    const int r0 = rp, r1 = rp + 16;
    const int b0 = bp, b1 = bp + 16;
    // cell mapping: thread -> (j = tid>>5 in [0,8), b = tid&31)
    const int jj = tid >> 5;
    const int bb = tid & 31;

    // global gate rows of this thread's two GEMM rows
    const int g0 = (r0 >> 3) * Hn + s * 8 + (r0 & 7);
    const int g1 = (r1 >> 3) * Hn + s * 8 + (r1 & 7);

    const float wi0 = Wih1[c * Gn + g0];
    const float wi1 = Wih1[c * Gn + g1];
    const float bs1_0 = bih1[c * Gn + g0] + bhh1[c * Gn + g0];
    const float bs1_1 = bih1[c * Gn + g1] + bhh1[c * Gn + g1];
    const float bs2_0 = bih2[c * Gn + g0] + bhh2[c * Gn + g0];
    const float bs2_1 = bih2[c * Gn + g1] + bhh2[c * Gn + g1];
    const float wl = Wlin[c * Hn + s * 8 + jj];
    const float bl = blin[c];

    const float* Whh1c = Whh1 + c * Gn * Hn;
    const float* Wih2c = Wih2 + c * Gn * Hn;
    const float* Whh2c = Whh2 + c * Gn * Hn;

    float c1 = 0.0f, c2 = 0.0f;         // cell states live in registers

    for (int t = 0; t <= Tn; ++t) {
        const bool doA = (t < Tn);      // layer-1 step t
        const bool doB = (t >= 1);      // layer-2 step t-1 (pipelined one behind)

        // S0: stage h1[t-1] (both phases use it) + Whh1 slice
        stage_h(hbuf, H1 + ((t + 1) & 1) * CBH + c * Bn * Hn, tid);
        if (doA) stage_w(wbuf, Whh1c, s, tid);
        __syncthreads();

        // S1: layer-1 gates
        if (doA) {
            float4 a00 = {0,0,0,0}, a01 = {0,0,0,0}, a10 = {0,0,0,0}, a11 = {0,0,0,0};
            gemm2x2(wbuf, hbuf, r0, r1, b0, b1, a00, a01, a10, a11);
            const float xv0 = x[(b0 * Tn + t) * Cn + c];
            const float xv1 = x[(b1 * Tn + t) * Cn + c];
            gbuf[r0 * 32 + b0] = sum4(a00) + xv0 * wi0 + bs1_0;
            gbuf[r0 * 32 + b1] = sum4(a01) + xv1 * wi0 + bs1_0;
            gbuf[r1 * 32 + b0] = sum4(a10) + xv0 * wi1 + bs1_1;
            gbuf[r1 * 32 + b1] = sum4(a11) + xv1 * wi1 + bs1_1;
        }
        __syncthreads();

        // S2: layer-1 cell; overlap staging Wih2 (wbuf reads all done)
        if (doA) {
            const float iv = sigmf(gbuf[jj * 32 + bb]);
            const float fv = sigmf(gbuf[(8 + jj) * 32 + bb]);
            const float gv = tanh_f(gbuf[(16 + jj) * 32 + bb]);
            const float ov = sigmf(gbuf[(24 + jj) * 32 + bb]);
            c1 = fv * c1 + iv * gv;
            hout[bb * 8 + jj] = ov * tanh_f(c1);
        }
        if (doB) stage_w(wbuf, Wih2c, s, tid);
        __syncthreads();

        // S3: write h1[t] to global (coalesced-ish); layer-2 input-proj GEMM on h1[t-1]
        if (doA) {
            float* hdst = H1 + (t & 1) * CBH + c * Bn * Hn;
            hdst[(tid >> 3) * Hn + s * 8 + (tid & 7)] = hout[tid];
        }
        float4 e00 = {0,0,0,0}, e01 = {0,0,0,0}, e10 = {0,0,0,0}, e11 = {0,0,0,0};
        if (doB) gemm2x2(wbuf, hbuf, r0, r1, b0, b1, e00, e01, e10, e11);
        __syncthreads();

        // S4: stage Whh2 + h2[t-2]
        if (doB) {
            stage_w(wbuf, Whh2c, s, tid);
            stage_h(hbuf, H2 + (t & 1) * CBH + c * Bn * Hn, tid);
        }
        __syncthreads();

        // S5: layer-2 recurrent GEMM, finish gates
        if (doB) {
            gemm2x2(wbuf, hbuf, r0, r1, b0, b1, e00, e01, e10, e11);
            gbuf[r0 * 32 + b0] = sum4(e00) + bs2_0;
            gbuf[r0 * 32 + b1] = sum4(e01) + bs2_0;
            gbuf[r1 * 32 + b0] = sum4(e10) + bs2_1;
            gbuf[r1 * 32 + b1] = sum4(e11) + bs2_1;
        }
        __syncthreads();

        // S6: layer-2 cell; out partial into own gbuf slot (safe: slot [jj][bb] only read by this thread)
        if (doB) {
            const float iv = sigmf(gbuf[jj * 32 + bb]);
            const float fv = sigmf(gbuf[(8 + jj) * 32 + bb]);
            const float gv = tanh_f(gbuf[(16 + jj) * 32 + bb]);
            const float ov = sigmf(gbuf[(24 + jj) * 32 + bb]);
            c2 = fv * c2 + iv * gv;
            const float h2v = ov * tanh_f(c2);
            hout[bb * 8 + jj] = h2v;
            gbuf[jj * 32 + bb] = h2v * wl;
        }
        __syncthreads();

        // S7: write h2[t-1] global; reduce out partials, one atomic per (b)
        if (doB) {
            float* hdst = H2 + ((t + 1) & 1) * CBH + c * Bn * Hn;
            hdst[(tid >> 3) * Hn + s * 8 + (tid & 7)] = hout[tid];
            if (tid < 32) {
                float v = 0.0f;
#pragma unroll
                for (int j = 0; j < 8; ++j) v += gbuf[j * 32 + tid];
                if (s == 0) v += bl;
                atomicAdd(&out[(tid * Tn + (t - 1)) * Cn + c], v);
            }
        }

        // per-channel barrier (32 wgs): publishes h1[t], h2[t-1] for next superstep
        chan_barrier(&bars[c * 16], (unsigned)(t + 1) * 32u);
    }
}

extern "C" void kernel_launch(void* const* d_in, const int* in_sizes, int n_in,
                              void* d_out, int out_size, void* d_ws, size_t ws_size,
                              hipStream_t stream) {
    const float* x    = (const float*)d_in[0];
    const float* Wih1 = (const float*)d_in[1];
    const float* Whh1 = (const float*)d_in[2];
    const float* bih1 = (const float*)d_in[3];
    const float* bhh1 = (const float*)d_in[4];
    const float* Wih2 = (const float*)d_in[5];
    const float* Whh2 = (const float*)d_in[6];
    const float* bih2 = (const float*)d_in[7];
    const float* bhh2 = (const float*)d_in[8];
    const float* Wlin = (const float*)d_in[9];
    const float* blin = (const float*)d_in[10];
    float* out = (float*)d_out;
    float* ws  = (float*)d_ws;

    // zero h-state double buffers + barrier counters (ws is poisoned 0xAA each call)
    const size_t ws_need = (size_t)4 * CBH * sizeof(float) + 4096;
    hipMemsetAsync(d_ws, 0, ws_need, stream);
    // out is accumulated with atomics -> zero it (poisoned 0xAA each call)
    hipMemsetAsync(d_out, 0, (size_t)out_size * sizeof(float), stream);

    const int lds_bytes = (32 * KP + 32 * KP + 32 * 32 + 256) * 4;  // 71680
    hipFuncSetAttribute(reinterpret_cast<const void*>(lstm_fused),
                        hipFuncAttributeMaxDynamicSharedMemorySize, lds_bytes);

    lstm_fused<<<NBLK, NTHR, lds_bytes, stream>>>(
        x, Wih1, Whh1, bih1, bhh1, Wih2, Whh2, bih2, bhh2, Wlin, blin, out, ws);
}

// Round 2
// 9432.320 us; speedup vs baseline: 1.6507x; 1.6507x over previous
//
#include <hip/hip_runtime.h>

#define Bn 32
#define Tn 512
#define Cn 8
#define Hn 256
#define Gn 1024           // 4*Hn
#define NTHR 256
#define NBLK 256          // 8 channels * 32 slices
#define CBHE (Cn*Bn*Hn)   // 65536 elements (one h snapshot, all channels)
#define HB2  (2*CBHE)     // double-buffered h array, in ushorts

typedef __attribute__((ext_vector_type(8))) __bf16 bf16x8;
typedef __attribute__((ext_vector_type(8))) short  short8;
typedef __attribute__((ext_vector_type(4))) float  f32x4;

__device__ __forceinline__ unsigned bfr(float f) {            // fp32 -> bf16 bits, RNE
    unsigned u = __float_as_uint(f);
    return (u + 0x7fffu + ((u >> 16) & 1u)) >> 16;
}
__device__ __forceinline__ float sigmf(float v)  { return 1.0f / (1.0f + __expf(-v)); }
__device__ __forceinline__ float tanh_f(float v) { return 1.0f - 2.0f / (__expf(2.0f * v) + 1.0f); }

__device__ __forceinline__ f32x4 mf(short8 a, short8 b, f32x4 c) {
    return __builtin_amdgcn_mfma_f32_16x16x32_bf16(
        __builtin_bit_cast(bf16x8, a), __builtin_bit_cast(bf16x8, b), c, 0, 0, 0);
}

// split 8 consecutive fp32 into bf16 hi + bf16 lo fragments
__device__ __forceinline__ void splitw(const float* __restrict__ p, short8& hi, short8& lo) {
    short8 h, l;
#pragma unroll
    for (int j = 0; j < 8; ++j) {
        const float v = p[j];
        const unsigned hb = bfr(v);
        const float hf = __uint_as_float(hb << 16);
        h[j] = (short)hb;
        l[j] = (short)bfr(v - hf);
    }
    hi = h; lo = l;
}

// per-channel barrier: 32 wgs, monotone counter, device-scope
__device__ __forceinline__ void chan_barrier(unsigned* cnt, unsigned target) {
    __syncthreads();
    if (threadIdx.x == 0) {
        __threadfence();
        atomicAdd(cnt, 1u);
        while (__hip_atomic_load(cnt, __ATOMIC_RELAXED, __HIP_MEMORY_SCOPE_AGENT) < target)
            __builtin_amdgcn_s_sleep(2);
        __threadfence();
    }
    __syncthreads();
}

__global__ void __launch_bounds__(NTHR, 1)
lstm_mfma(const float* __restrict__ x,
          const float* __restrict__ Wih1, const float* __restrict__ Whh1,
          const float* __restrict__ bih1, const float* __restrict__ bhh1,
          const float* __restrict__ Wih2, const float* __restrict__ Whh2,
          const float* __restrict__ bih2, const float* __restrict__ bhh2,
          const float* __restrict__ Wlin, const float* __restrict__ blin,
          float* __restrict__ out, void* __restrict__ wsv) {
    __shared__ float g1buf[32 * 33];   // layer-1 gate exchange (rows x batches, padded)
    __shared__ float g2buf[32 * 33];   // layer-2 gate exchange

    unsigned short* H1h = (unsigned short*)wsv;  // [2][C][B][H] bf16-hi of h1, double-buffered
    unsigned short* H1l = H1h + HB2;
    unsigned short* H2h = H1l + HB2;
    unsigned short* H2l = H2h + HB2;
    unsigned* bars = (unsigned*)(H2l + HB2);     // 8 counters, 64B apart

    const int tid  = threadIdx.x;
    const int wg   = blockIdx.x;
    const int c    = wg & 7;            // channel (XCD-local: blocks i, i+8, ... share an XCD)
    const int s    = wg >> 3;           // slice: h-indices s*8 .. s*8+7
    const int lane = tid & 63;
    const int wid  = tid >> 6;
    const int n    = lane & 15;
    const int quad = lane >> 4;
    const int rbase = (wid & 1) * 16;   // wave's gate-row half
    const int bbase = (wid >> 1) * 16;  // wave's batch half

    // ---- permanent A-fragments: all three weight matrices, bf16 hi+lo, in VGPRs ----
    // A[m][k]: m = rbase+n (lane), k = kk*32 + quad*8 + j
    const int mrow = rbase + n;                                  // row within wg tile (0..31)
    const size_t gm = (size_t)((mrow >> 3) * Hn + s * 8 + (mrow & 7)); // global gate row
    short8 w1h[8], w1l[8], w2h[8], w2l[8], w3h[8], w3l[8];
    {
        const size_t wbase = (size_t)c * Gn * Hn + gm * Hn + quad * 8;
        const float* p1 = Whh1 + wbase;
        const float* p2 = Wih2 + wbase;
        const float* p3 = Whh2 + wbase;
#pragma unroll
        for (int kk = 0; kk < 8; ++kk) {
            splitw(p1 + kk * 32, w1h[kk], w1l[kk]);
            splitw(p2 + kk * 32, w2h[kk], w2l[kk]);
            splitw(p3 + kk * 32, w3h[kk], w3l[kk]);
        }
    }

    // per-lane epilogue constants for the 4 accumulator rows (row = rbase + quad*4 + reg)
    float wi1_r[4], bs1_r[4], bs2_r[4];
#pragma unroll
    for (int reg = 0; reg < 4; ++reg) {
        const int r = rbase + quad * 4 + reg;
        const int g = (r >> 3) * Hn + s * 8 + (r & 7);
        wi1_r[reg] = Wih1[c * Gn + g];
        bs1_r[reg] = bih1[c * Gn + g] + bhh1[c * Gn + g];
        bs2_r[reg] = bih2[c * Gn + g] + bhh2[c * Gn + g];
    }

    // cell-update mapping: thread -> (jj = tid&7 h-idx within slice, bb = tid>>3 batch)
    const int jj = tid & 7;
    const int bb = tid >> 3;
    const float wl = Wlin[c * Hn + s * 8 + jj];
    const float bl = blin[c];

    float c1 = 0.0f, c2 = 0.0f;

    for (int t = 0; t <= Tn; ++t) {
        const bool doA = (t < Tn);      // layer-1 step t
        const bool doB = (t >= 1);      // layer-2 step t-1 (pipelined one behind)
        const int rd1 = (t + 1) & 1, wr1 = t & 1;        // h1 buffers
        const int rd2 = t & 1,       wr2 = (t + 1) & 1;  // h2 buffers

        // ---- B-fragments of h2[t-2] (pre-split bf16 in global) ----
        const int hoff2 = ((rd2 * Cn + c) * Bn + (bbase + n)) * Hn + quad * 8;
        short8 f2h[8], f2l[8];
#pragma unroll
        for (int kk = 0; kk < 8; ++kk) {
            f2h[kk] = *(const short8*)(H2h + hoff2 + kk * 32);
            f2l[kk] = *(const short8*)(H2l + hoff2 + kk * 32);
        }
        f32x4 a2a = {0,0,0,0}, a2b = {0,0,0,0}, a2c = {0,0,0,0};
#pragma unroll
        for (int kk = 0; kk < 8; ++kk) {            // Whh2 . h2[t-2]
            a2a = mf(w3h[kk], f2h[kk], a2a);
            a2b = mf(w3h[kk], f2l[kk], a2b);
            a2c = mf(w3l[kk], f2h[kk], a2c);
        }

        // ---- B-fragments of h1[t-1] ----
        const int hoff1 = ((rd1 * Cn + c) * Bn + (bbase + n)) * Hn + quad * 8;
        short8 f1h[8], f1l[8];
#pragma unroll
        for (int kk = 0; kk < 8; ++kk) {
            f1h[kk] = *(const short8*)(H1h + hoff1 + kk * 32);
            f1l[kk] = *(const short8*)(H1l + hoff1 + kk * 32);
        }
        f32x4 a1a = {0,0,0,0}, a1b = {0,0,0,0}, a1c = {0,0,0,0};
#pragma unroll
        for (int kk = 0; kk < 8; ++kk) {            // Whh1 . h1[t-1]  and  Wih2 . h1[t-1]
            a1a = mf(w1h[kk], f1h[kk], a1a);
            a1b = mf(w1h[kk], f1l[kk], a1b);
            a1c = mf(w1l[kk], f1h[kk], a1c);
            a2a = mf(w2h[kk], f1h[kk], a2a);
            a2b = mf(w2h[kk], f1l[kk], a2b);
            a2c = mf(w2l[kk], f1h[kk], a2c);
        }

        const float xv = doA ? x[((bbase + n) * Tn + t) * Cn + c] : 0.0f;

        // ---- write gates to LDS (C/D layout: col = lane&15, row = quad*4+reg) ----
#pragma unroll
        for (int reg = 0; reg < 4; ++reg) {
            const int r = rbase + quad * 4 + reg;
            g1buf[r * 33 + bbase + n] = a1a[reg] + a1b[reg] + a1c[reg] + xv * wi1_r[reg] + bs1_r[reg];
            g2buf[r * 33 + bbase + n] = a2a[reg] + a2b[reg] + a2c[reg] + bs2_r[reg];
        }
        __syncthreads();

        // ---- layer-1 cell update, publish h1[t] as split bf16 ----
        if (doA) {
            const float iv = sigmf(g1buf[jj * 33 + bb]);
            const float fv = sigmf(g1buf[(8 + jj) * 33 + bb]);
            const float gv = tanh_f(g1buf[(16 + jj) * 33 + bb]);
            const float ov = sigmf(g1buf[(24 + jj) * 33 + bb]);
            c1 = fv * c1 + iv * gv;
            const float h1v = ov * tanh_f(c1);
            const unsigned hb = bfr(h1v);
            const float hf = __uint_as_float(hb << 16);
            const unsigned lb = bfr(h1v - hf);
            const int idx = ((wr1 * Cn + c) * Bn + bb) * Hn + s * 8 + jj;
            H1h[idx] = (unsigned short)hb;
            H1l[idx] = (unsigned short)lb;
        }
        // ---- layer-2 cell update, publish h2[t-1], accumulate output ----
        if (doB) {
            const float iv = sigmf(g2buf[jj * 33 + bb]);
            const float fv = sigmf(g2buf[(8 + jj) * 33 + bb]);
            const float gv = tanh_f(g2buf[(16 + jj) * 33 + bb]);
            const float ov = sigmf(g2buf[(24 + jj) * 33 + bb]);
            c2 = fv * c2 + iv * gv;
            const float h2v = ov * tanh_f(c2);
            const unsigned hb = bfr(h2v);
            const float hf = __uint_as_float(hb << 16);
            const unsigned lb = bfr(h2v - hf);
            const int idx = ((wr2 * Cn + c) * Bn + bb) * Hn + s * 8 + jj;
            H2h[idx] = (unsigned short)hb;
            H2l[idx] = (unsigned short)lb;

            float pv = h2v * wl;                      // partial of out over this slice's 8 h
            pv += __shfl_xor(pv, 1, 64);
            pv += __shfl_xor(pv, 2, 64);
            pv += __shfl_xor(pv, 4, 64);
            if (jj == 0) {
                const float v = pv + (s == 0 ? bl : 0.0f);
                atomicAdd(&out[(bb * Tn + (t - 1)) * Cn + c], v);
            }
        }

        // publish h1[t], h2[t-1] to the channel's 32 wgs
        chan_barrier(&bars[c * 16], (unsigned)(t + 1) * 32u);
    }
}

extern "C" void kernel_launch(void* const* d_in, const int* in_sizes, int n_in,
                              void* d_out, int out_size, void* d_ws, size_t ws_size,
                              hipStream_t stream) {
    const float* x    = (const float*)d_in[0];
    const float* Wih1 = (const float*)d_in[1];
    const float* Whh1 = (const float*)d_in[2];
    const float* bih1 = (const float*)d_in[3];
    const float* bhh1 = (const float*)d_in[4];
    const float* Wih2 = (const float*)d_in[5];
    const float* Whh2 = (const float*)d_in[6];
    const float* bih2 = (const float*)d_in[7];
    const float* bhh2 = (const float*)d_in[8];
    const float* Wlin = (const float*)d_in[9];
    const float* blin = (const float*)d_in[10];
    float* out = (float*)d_out;

    // 4 split-h arrays (2B each elem, double-buffered) + barrier counters; zero them
    const size_t ws_need = (size_t)4 * HB2 * sizeof(unsigned short) + 4096;  // 1 MiB + 4 KiB
    hipMemsetAsync(d_ws, 0, ws_need, stream);
    hipMemsetAsync(d_out, 0, (size_t)out_size * sizeof(float), stream);  // atomics accumulate

    lstm_mfma<<<NBLK, NTHR, 0, stream>>>(
        x, Wih1, Whh1, bih1, bhh1, Wih2, Whh2, bih2, bhh2, Wlin, blin, out, d_ws);
}

// Round 3
// 7048.441 us; speedup vs baseline: 2.2090x; 1.3382x over previous
//
#include <hip/hip_runtime.h>

#define Bn 32
#define Tn 512
#define Cn 8
#define Hn 256
#define Gn 1024           // 4*Hn
#define NTHR 512          // 8 waves: 4 row-groups x 2 batch-groups
#define NSL  16           // slices per channel (each owns 16 h-indices)
#define NBLK (Cn*NSL)     // 128 workgroups
#define CBHE (Cn*Bn*Hn)   // 65536 elements (one h snapshot, all channels)
#define HB2  (2*CBHE)     // double-buffered h array, in ushorts
#define GP   36           // gate-buffer pitch (floats): 2-way banks on write & read

typedef __attribute__((ext_vector_type(8))) __bf16 bf16x8;
typedef __attribute__((ext_vector_type(8))) short  short8;
typedef __attribute__((ext_vector_type(4))) float  f32x4;

__device__ __forceinline__ unsigned bfr(float f) {            // fp32 -> bf16 bits, RNE
    unsigned u = __float_as_uint(f);
    return (u + 0x7fffu + ((u >> 16) & 1u)) >> 16;
}
__device__ __forceinline__ float sigmf(float v)  { return 1.0f / (1.0f + __expf(-v)); }
__device__ __forceinline__ float tanh_f(float v) { return 1.0f - 2.0f / (__expf(2.0f * v) + 1.0f); }

__device__ __forceinline__ f32x4 mf(short8 a, short8 b, f32x4 c) {
    return __builtin_amdgcn_mfma_f32_16x16x32_bf16(
        __builtin_bit_cast(bf16x8, a), __builtin_bit_cast(bf16x8, b), c, 0, 0, 0);
}

// split 8 consecutive fp32 into bf16 hi + bf16 lo fragments
__device__ __forceinline__ void splitw(const float* __restrict__ p, short8& hi, short8& lo) {
    short8 h, l;
#pragma unroll
    for (int j = 0; j < 8; ++j) {
        const float v = p[j];
        const unsigned hb = bfr(v);
        const float hf = __uint_as_float(hb << 16);
        h[j] = (short)hb;
        l[j] = (short)bfr(v - hf);
    }
    hi = h; lo = l;
}

__global__ void __launch_bounds__(NTHR, 2)
lstm_mfma(const float* __restrict__ x,
          const float* __restrict__ Wih1, const float* __restrict__ Whh1,
          const float* __restrict__ bih1, const float* __restrict__ bhh1,
          const float* __restrict__ Wih2, const float* __restrict__ Whh2,
          const float* __restrict__ bih2, const float* __restrict__ bhh2,
          const float* __restrict__ Wlin, const float* __restrict__ blin,
          float* __restrict__ out, void* __restrict__ wsv, int use_part) {
    __shared__ float g1buf[64 * GP];   // layer-1 gate exchange (64 rows x 32 batches, padded)
    __shared__ float g2buf[64 * GP];   // layer-2 gate exchange

    unsigned short* H1h = (unsigned short*)wsv;  // [2][C][B][H] bf16-hi of h1
    unsigned short* H1l = H1h + HB2;
    unsigned short* H2h = H1l + HB2;
    unsigned short* H2l = H2h + HB2;
    unsigned* flags = (unsigned*)(H2l + HB2);    // [C][NSL] monotone flags, 256B apart
    float* part = (float*)(flags + Cn * NSL * 64);  // [T][C][NSL][B] out partials

    const int tid  = threadIdx.x;
    const int wg   = blockIdx.x;
    const int c    = wg & 7;            // channel (all 16 wgs of a channel on one XCD)
    const int s    = wg >> 3;           // slice: h-indices s*16 .. s*16+15
    const int lane = tid & 63;
    const int wid  = tid >> 6;          // 0..7
    const int n    = lane & 15;
    const int quad = lane >> 4;
    const int rbase = (wid & 3) * 16;   // wave's gate-row group (rows 0..63)
    const int bbase = (wid >> 2) * 16;  // wave's batch half

    // ---- permanent A-fragments: all three weight matrices, bf16 hi+lo, in VGPRs ----
    const int mrow = rbase + n;                                       // wg row (0..63)
    const size_t gm = (size_t)((mrow >> 4) * Hn + s * NSL + (mrow & 15)); // global gate row
    short8 w1h[8], w1l[8], w2h[8], w2l[8], w3h[8], w3l[8];
    {
        const size_t wbase = (size_t)c * Gn * Hn + gm * Hn + quad * 8;
        const float* p1 = Whh1 + wbase;
        const float* p2 = Wih2 + wbase;
        const float* p3 = Whh2 + wbase;
#pragma unroll
        for (int kk = 0; kk < 8; ++kk) {
            splitw(p1 + kk * 32, w1h[kk], w1l[kk]);
            splitw(p2 + kk * 32, w2h[kk], w2l[kk]);
            splitw(p3 + kk * 32, w3h[kk], w3l[kk]);
        }
    }

    // per-lane epilogue constants for the 4 accumulator rows (row = rbase + quad*4 + reg)
    float wi1_r[4], bs1_r[4], bs2_r[4];
#pragma unroll
    for (int reg = 0; reg < 4; ++reg) {
        const int r = rbase + quad * 4 + reg;
        const int g = (r >> 4) * Hn + s * NSL + (r & 15);
        wi1_r[reg] = Wih1[c * Gn + g];
        bs1_r[reg] = bih1[c * Gn + g] + bhh1[c * Gn + g];
        bs2_r[reg] = bih2[c * Gn + g] + bhh2[c * Gn + g];
    }

    // cell-update mapping: thread -> (jj = tid&15 h-idx within slice, bb = tid>>4 batch)
    const int jj = tid & 15;
    const int bb = tid >> 4;
    const float wl = Wlin[c * Hn + s * NSL + jj];
    const float bl = blin[c];

    float c1 = 0.0f, c2 = 0.0f;

    for (int t = 0; t <= Tn; ++t) {
        const bool doA = (t < Tn);      // layer-1 step t
        const bool doB = (t >= 1);      // layer-2 step t-1 (pipelined one behind)
        const int rd1 = (t + 1) & 1, wr1 = t & 1;        // h1 buffers
        const int rd2 = t & 1,       wr2 = (t + 1) & 1;  // h2 buffers

        // ---- B-fragments of h2[t-2] ----
        const int hoff2 = ((rd2 * Cn + c) * Bn + (bbase + n)) * Hn + quad * 8;
        short8 f2h[8], f2l[8];
#pragma unroll
        for (int kk = 0; kk < 8; ++kk) {
            f2h[kk] = *(const short8*)(H2h + hoff2 + kk * 32);
            f2l[kk] = *(const short8*)(H2l + hoff2 + kk * 32);
        }
        f32x4 a2a = {0,0,0,0}, a2b = {0,0,0,0}, a2c = {0,0,0,0};
#pragma unroll
        for (int kk = 0; kk < 8; ++kk) {            // Whh2 . h2[t-2]
            a2a = mf(w3h[kk], f2h[kk], a2a);
            a2b = mf(w3h[kk], f2l[kk], a2b);
            a2c = mf(w3l[kk], f2h[kk], a2c);
        }

        // ---- B-fragments of h1[t-1] ----
        const int hoff1 = ((rd1 * Cn + c) * Bn + (bbase + n)) * Hn + quad * 8;
        short8 f1h[8], f1l[8];
#pragma unroll
        for (int kk = 0; kk < 8; ++kk) {
            f1h[kk] = *(const short8*)(H1h + hoff1 + kk * 32);
            f1l[kk] = *(const short8*)(H1l + hoff1 + kk * 32);
        }
        f32x4 a1a = {0,0,0,0}, a1b = {0,0,0,0}, a1c = {0,0,0,0};
#pragma unroll
        for (int kk = 0; kk < 8; ++kk) {            // Whh1 . h1[t-1]  and  Wih2 . h1[t-1]
            a1a = mf(w1h[kk], f1h[kk], a1a);
            a1b = mf(w1h[kk], f1l[kk], a1b);
            a1c = mf(w1l[kk], f1h[kk], a1c);
            a2a = mf(w2h[kk], f1h[kk], a2a);
            a2b = mf(w2h[kk], f1l[kk], a2b);
            a2c = mf(w2l[kk], f1h[kk], a2c);
        }

        const float xv = doA ? x[((bbase + n) * Tn + t) * Cn + c] : 0.0f;

        // ---- write gates to LDS (C/D layout: col = lane&15, row = quad*4+reg) ----
#pragma unroll
        for (int reg = 0; reg < 4; ++reg) {
            const int r = rbase + quad * 4 + reg;
            g1buf[r * GP + bbase + n] = a1a[reg] + a1b[reg] + a1c[reg] + xv * wi1_r[reg] + bs1_r[reg];
            g2buf[r * GP + bbase + n] = a2a[reg] + a2b[reg] + a2c[reg] + bs2_r[reg];
        }
        __syncthreads();

        // ---- layer-1 cell update, publish h1[t] as split bf16 ----
        if (doA) {
            const float iv = sigmf(g1buf[jj * GP + bb]);
            const float fv = sigmf(g1buf[(16 + jj) * GP + bb]);
            const float gv = tanh_f(g1buf[(32 + jj) * GP + bb]);
            const float ov = sigmf(g1buf[(48 + jj) * GP + bb]);
            c1 = fv * c1 + iv * gv;
            const float h1v = ov * tanh_f(c1);
            const unsigned hb = bfr(h1v);
            const float hf = __uint_as_float(hb << 16);
            const unsigned lb = bfr(h1v - hf);
            const int idx = ((wr1 * Cn + c) * Bn + bb) * Hn + s * NSL + jj;
            H1h[idx] = (unsigned short)hb;
            H1l[idx] = (unsigned short)lb;
        }
        // ---- layer-2 cell update, publish h2[t-1], out partial ----
        if (doB) {
            const float iv = sigmf(g2buf[jj * GP + bb]);
            const float fv = sigmf(g2buf[(16 + jj) * GP + bb]);
            const float gv = tanh_f(g2buf[(32 + jj) * GP + bb]);
            const float ov = sigmf(g2buf[(48 + jj) * GP + bb]);
            c2 = fv * c2 + iv * gv;
            const float h2v = ov * tanh_f(c2);
            const unsigned hb = bfr(h2v);
            const float hf = __uint_as_float(hb << 16);
            const unsigned lb = bfr(h2v - hf);
            const int idx = ((wr2 * Cn + c) * Bn + bb) * Hn + s * NSL + jj;
            H2h[idx] = (unsigned short)hb;
            H2l[idx] = (unsigned short)lb;

            float pv = h2v * wl;                      // partial of out over this slice's 16 h
            pv += __shfl_xor(pv, 1, 64);
            pv += __shfl_xor(pv, 2, 64);
            pv += __shfl_xor(pv, 4, 64);
            pv += __shfl_xor(pv, 8, 64);
            if (jj == 0) {
                if (use_part) {
                    part[(((t - 1) * Cn + c) * NSL + s) * Bn + bb] = pv;
                } else {
                    atomicAdd(&out[(bb * Tn + (t - 1)) * Cn + c], pv + (s == 0 ? bl : 0.0f));
                }
            }
        }

        // ---- flag barrier: 16 independent flag lines, no RMW chain ----
        __syncthreads();                 // drain all waves' h stores into L2
        if (tid == 0) {
            __threadfence();             // push dirty L2 to coherence point (release)
            __hip_atomic_store(&flags[(c * NSL + s) * 64], (unsigned)(t + 1),
                               __ATOMIC_RELAXED, __HIP_MEMORY_SCOPE_AGENT);
            bool ready = false;
            while (!ready) {
                bool ok = true;
#pragma unroll
                for (int s2 = 0; s2 < NSL; ++s2)
                    ok &= (__hip_atomic_load(&flags[(c * NSL + s2) * 64],
                                             __ATOMIC_RELAXED, __HIP_MEMORY_SCOPE_AGENT)
                           >= (unsigned)(t + 1));
                ready = ok;
                if (!ready) __builtin_amdgcn_s_sleep(1);
            }
            __threadfence();             // invalidate stale lines (acquire)
        }
        __syncthreads();
    }
}

__global__ void reduce_out(const float* __restrict__ part, const float* __restrict__ blin,
                           float* __restrict__ out) {
    const int t = blockIdx.x;           // 512
    const int c = threadIdx.x >> 5;     // 8
    const int b = threadIdx.x & 31;     // 32
    float v = blin[c];
#pragma unroll
    for (int s = 0; s < NSL; ++s) v += part[((t * Cn + c) * NSL + s) * Bn + b];
    out[(b * Tn + t) * Cn + c] = v;
}

extern "C" void kernel_launch(void* const* d_in, const int* in_sizes, int n_in,
                              void* d_out, int out_size, void* d_ws, size_t ws_size,
                              hipStream_t stream) {
    const float* x    = (const float*)d_in[0];
    const float* Wih1 = (const float*)d_in[1];
    const float* Whh1 = (const float*)d_in[2];
    const float* bih1 = (const float*)d_in[3];
    const float* bhh1 = (const float*)d_in[4];
    const float* Wih2 = (const float*)d_in[5];
    const float* Whh2 = (const float*)d_in[6];
    const float* bih2 = (const float*)d_in[7];
    const float* bhh2 = (const float*)d_in[8];
    const float* Wlin = (const float*)d_in[9];
    const float* blin = (const float*)d_in[10];
    float* out = (float*)d_out;

    const size_t h_bytes    = (size_t)4 * HB2 * sizeof(unsigned short);     // 1 MiB
    const size_t flag_bytes = (size_t)Cn * NSL * 64 * sizeof(unsigned);     // 32 KiB
    const size_t part_bytes = (size_t)Tn * Cn * NSL * Bn * sizeof(float);   // 8 MiB
    const int use_part = (ws_size >= h_bytes + flag_bytes + part_bytes) ? 1 : 0;

    hipMemsetAsync(d_ws, 0, h_bytes + flag_bytes, stream);   // zero h state + flags
    if (!use_part)
        hipMemsetAsync(d_out, 0, (size_t)out_size * sizeof(float), stream);

    lstm_mfma<<<NBLK, NTHR, 0, stream>>>(
        x, Wih1, Whh1, bih1, bhh1, Wih2, Whh2, bih2, bhh2, Wlin, blin, out, d_ws, use_part);

    if (use_part) {
        const float* part = (const float*)((const char*)d_ws + h_bytes + flag_bytes);
        reduce_out<<<Tn, Cn * Bn, 0, stream>>>(part, blin, out);
    }
}